// Round 4
// baseline (308.911 us; speedup 1.0000x reference)
//
#include <hip/hip_runtime.h>
#include <stdint.h>

// B=8, S=1024, H=1024, NH=16, HD=64
typedef __attribute__((ext_vector_type(8))) __bf16 bf16x8;
typedef __attribute__((ext_vector_type(8))) unsigned short ushortx8;
typedef __attribute__((ext_vector_type(4))) unsigned short ushortx4;
typedef __attribute__((ext_vector_type(4))) short short4v;
typedef __attribute__((ext_vector_type(4))) float floatx4;

#define ASYNC16(g, l) __builtin_amdgcn_global_load_lds( \
    (__attribute__((address_space(1))) void*)(g),       \
    (__attribute__((address_space(3))) void*)(l), 16, 0, 0)

__device__ __forceinline__ unsigned short f2bf(float f) {
    unsigned int u = __float_as_uint(f);
    u += 0x7fffu + ((u >> 16) & 1u);   // round-to-nearest-even
    return (unsigned short)(u >> 16);
}

__device__ __forceinline__ floatx4 mfma32(bf16x8 a, bf16x8 b, floatx4 c) {
    return __builtin_amdgcn_mfma_f32_16x16x32_bf16(a, b, c, 0, 0, 0);
}
__device__ __forceinline__ floatx4 mfma16(short4v a, short4v b, floatx4 c) {
    return __builtin_amdgcn_mfma_f32_16x16x16bf16_1k(a, b, c, 0, 0, 0);
}

// ---------------- fp32 -> bf16 converts ----------------
__global__ __launch_bounds__(256) void cvt_bf16(const float* __restrict__ in,
                                                unsigned short* __restrict__ out,
                                                int n8) {
    int i = blockIdx.x * 256 + threadIdx.x;
    if (i >= n8) return;
    const float4* p = (const float4*)in + (size_t)i * 2;
    float4 a = p[0], b = p[1];
    ushortx8 o;
    o[0] = f2bf(a.x); o[1] = f2bf(a.y); o[2] = f2bf(a.z); o[3] = f2bf(a.w);
    o[4] = f2bf(b.x); o[5] = f2bf(b.y); o[6] = f2bf(b.z); o[7] = f2bf(b.w);
    *((ushortx8*)out + i) = o;
}

// all 4 weight matrices in one launch: grid 2048, 512 blocks each
__global__ __launch_bounds__(256) void cvt_w(const float* __restrict__ Wq,
                                             const float* __restrict__ Wk,
                                             const float* __restrict__ Wv,
                                             const float* __restrict__ Wo,
                                             unsigned short* __restrict__ oqkv,
                                             unsigned short* __restrict__ oo) {
    int blk = blockIdx.x >> 9;
    const float* src = (blk == 0) ? Wq : (blk == 1) ? Wk : (blk == 2) ? Wv : Wo;
    unsigned short* dst = (blk == 3) ? oo : oqkv + (size_t)blk * 1048576;
    int i = (blockIdx.x & 511) * 256 + threadIdx.x;   // < 131072
    const float4* p = (const float4*)src + (size_t)i * 2;
    float4 a = p[0], b = p[1];
    ushortx8 o;
    o[0] = f2bf(a.x); o[1] = f2bf(a.y); o[2] = f2bf(a.z); o[3] = f2bf(a.w);
    o[4] = f2bf(b.x); o[5] = f2bf(b.y); o[6] = f2bf(b.z); o[7] = f2bf(b.w);
    *((ushortx8*)dst + i) = o;
}

// Shared K-loop: 128x128 tile, BK=32, swizzled LDS (phys chunk p of row r holds
// logical chunk p^((r>>1)&3) -> 2-way max bank aliasing = free).
// SWAP=false: acc[mt][nt], C row = A-row (m), col = W-row (n).
// SWAP=true : acc[ft][st], C row = W-row (feat), col = A-row (s).
template<bool SWAP>
__device__ __forceinline__ void kloop_128(
    const unsigned short* __restrict__ Ag,  // lane-ptr into A (hidden)
    const unsigned short* __restrict__ Wg,  // lane-ptr into W
    unsigned short* As, unsigned short* Bs,
    int wm, int wn, int l16, int quad, int t,
    floatx4 acc[4][4])
{
    const int K = 1024;
#pragma unroll 1
    for (int k0 = 0; k0 < K; k0 += 32) {
        __syncthreads();
        ASYNC16(Ag + k0,          As + t * 8);
        ASYNC16(Ag + 64 * K + k0, As + 2048 + t * 8);
        ASYNC16(Wg + k0,          Bs + t * 8);
        ASYNC16(Wg + 64 * K + k0, Bs + 2048 + t * 8);
        __syncthreads();
        bf16x8 af[4], bfr[4];
#pragma unroll
        for (int mt = 0; mt < 4; mt++) {
            int row = wm + mt * 16 + l16;
            int p = quad ^ ((row >> 1) & 3);
            af[mt] = *(const bf16x8*)(As + row * 32 + p * 8);
        }
#pragma unroll
        for (int nt = 0; nt < 4; nt++) {
            int row = wn + nt * 16 + l16;
            int p = quad ^ ((row >> 1) & 3);
            bfr[nt] = *(const bf16x8*)(Bs + row * 32 + p * 8);
        }
        if (SWAP) {
#pragma unroll
            for (int ft = 0; ft < 4; ft++)
#pragma unroll
                for (int st = 0; st < 4; st++)
                    acc[ft][st] = mfma32(bfr[ft], af[st], acc[ft][st]);
        } else {
#pragma unroll
            for (int mt = 0; mt < 4; mt++)
#pragma unroll
                for (int nt = 0; nt < 4; nt++)
                    acc[mt][nt] = mfma32(af[mt], bfr[nt], acc[mt][nt]);
        }
    }
}

// swizzled source column chunk for staging thread t (row = t>>2, log chunk = t&3)
__device__ __forceinline__ int stage_col(int t) { return ((t & 3) ^ ((t >> 3) & 3)) * 8; }

// ---------------- Q,K GEMM (transposed compute -> vector scatter) ----------------
// grid (64,16): y<8 -> Q, y>=8 -> K. W = [Wq;Wk] rows 0..2047.
__global__ __launch_bounds__(256) void gemm_qk(
    const unsigned short* __restrict__ A,   // [8192][1024] bf16
    const unsigned short* __restrict__ W,   // [2048][1024] bf16
    const float* __restrict__ bq, const float* __restrict__ bk,
    unsigned short* __restrict__ Qo, unsigned short* __restrict__ Ko)
{
    __shared__ unsigned short As[128 * 32];
    __shared__ unsigned short Bs[128 * 32];
    const int K = 1024;
    const int t = threadIdx.x;
    const int wave = t >> 6, lane = t & 63;
    const int quad = lane >> 4, l16 = lane & 15;
    const int wm = (wave >> 1) * 64, wn = (wave & 1) * 64;

    const unsigned short* Ag = A + (size_t)blockIdx.x * 128 * K + (t >> 2) * K + stage_col(t);
    const unsigned short* Wg = W + (size_t)blockIdx.y * 128 * K + (t >> 2) * K + stage_col(t);

    floatx4 acc[4][4] = {};
    kloop_128<true>(Ag, Wg, As, Bs, wm, wn, l16, quad, t, acc);

    const float* bp = (blockIdx.y < 8) ? bq : bk;
    unsigned short* op = (blockIdx.y < 8) ? Qo : Ko;
#pragma unroll
    for (int ft = 0; ft < 4; ft++) {
        int featg = (blockIdx.y * 128 + wn + ft * 16 + quad * 4) & 1023;
        float4 b4 = *(const float4*)(bp + featg);
        int h = featg >> 6, d = featg & 63;
#pragma unroll
        for (int st = 0; st < 4; st++) {
            int sg = blockIdx.x * 128 + wm + st * 16 + l16;
            int b = sg >> 10, s = sg & 1023;
            ushortx4 o4;
            o4[0] = f2bf(acc[ft][st][0] + b4.x);
            o4[1] = f2bf(acc[ft][st][1] + b4.y);
            o4[2] = f2bf(acc[ft][st][2] + b4.z);
            o4[3] = f2bf(acc[ft][st][3] + b4.w);
            *(ushortx4*)(op + (((size_t)(b * 16 + h) * 1024 + s) * 64 + d)) = o4;
        }
    }
}

// ---------------- V GEMM (normal compute -> transposed [b,h,d,s] vector scatter) ------
// grid (64,8). W = Wv rows.
__global__ __launch_bounds__(256) void gemm_v(
    const unsigned short* __restrict__ A,
    const unsigned short* __restrict__ W,   // [1024][1024] (Wv)
    const float* __restrict__ bv,
    unsigned short* __restrict__ Vo)        // [b,h,d,s]
{
    __shared__ unsigned short As[128 * 32];
    __shared__ unsigned short Bs[128 * 32];
    const int K = 1024;
    const int t = threadIdx.x;
    const int wave = t >> 6, lane = t & 63;
    const int quad = lane >> 4, l16 = lane & 15;
    const int wm = (wave >> 1) * 64, wn = (wave & 1) * 64;

    const unsigned short* Ag = A + (size_t)blockIdx.x * 128 * K + (t >> 2) * K + stage_col(t);
    const unsigned short* Wg = W + (size_t)blockIdx.y * 128 * K + (t >> 2) * K + stage_col(t);

    floatx4 acc[4][4] = {};
    kloop_128<false>(Ag, Wg, As, Bs, wm, wn, l16, quad, t, acc);

#pragma unroll
    for (int nt = 0; nt < 4; nt++) {
        int feat = (blockIdx.y * 128 + wn + nt * 16 + l16) & 1023;
        float bias = bv[feat];
        int h = feat >> 6, d = feat & 63;
#pragma unroll
        for (int mt = 0; mt < 4; mt++) {
            int sg = blockIdx.x * 128 + wm + mt * 16 + quad * 4;
            int b = sg >> 10, s = sg & 1023;
            ushortx4 o4;
#pragma unroll
            for (int r = 0; r < 4; r++) o4[r] = f2bf(acc[mt][nt][r] + bias);
            *(ushortx4*)(Vo + (((size_t)(b * 16 + h) * 64 + d) * 1024 + s)) = o4;
        }
    }
}

// ---------------- flash attention (S^T = K Q^T, no online max, swizzled ASYNC staging) ----
__global__ __launch_bounds__(256) void attn(
    const unsigned short* __restrict__ Q,   // [b,h,s,d]
    const unsigned short* __restrict__ Kg,  // [b,h,s,d]
    const unsigned short* __restrict__ Vt,  // [b,h,d,s]  (transposed)
    const float* __restrict__ mask,         // [B][S]
    unsigned short* __restrict__ ctx)       // [B,S,H] bf16
{
    __shared__ unsigned short Qs[64 * 64];
    __shared__ unsigned short Ks[64 * 64];
    __shared__ unsigned short Vs[64 * 64];  // [d][k]
    __shared__ float Msall[1024];

    const int t = threadIdx.x;
    const int wave = t >> 6, lane = t & 63, quad = lane >> 4, l16 = lane & 15;
    const int s7 = l16 & 7;
    const int head = blockIdx.y;
    const int b = head >> 4, h = head & 15;
    const int q0 = blockIdx.x * 64;
    const unsigned short* Qh = Q + (size_t)head * 65536;
    const unsigned short* Kh = Kg + (size_t)head * 65536;
    const unsigned short* Vh = Vt + (size_t)head * 65536;

    *(float4*)(Msall + t * 4) = *(const float4*)(mask + b * 1024 + t * 4);

    {
        int row = t >> 3, cg = (t & 7) ^ (row & 7);
        ASYNC16(Qh + (size_t)(q0 + row) * 64 + cg * 8, Qs + t * 8);
        ASYNC16(Qh + (size_t)(q0 + row + 32) * 64 + cg * 8, Qs + 2048 + t * 8);
    }
    __syncthreads();
    int qrow = wave * 16 + l16;
    bf16x8 qf0 = *(const bf16x8*)(Qs + qrow * 64 + ((quad ^ s7) * 8));
    bf16x8 qf1 = *(const bf16x8*)(Qs + qrow * 64 + (((quad + 4) ^ s7) * 8));

    float rs_acc = 0.f;
    floatx4 o_acc[4] = {};   // O^T: rows d = dt*16+quad*4+r, col q = l16

    for (int k0 = 0; k0 < 1024; k0 += 64) {
        __syncthreads();
        {
            int row = t >> 3, cg = (t & 7) ^ (row & 7);
            ASYNC16(Kh + (size_t)(k0 + row) * 64 + cg * 8, Ks + t * 8);
            ASYNC16(Kh + (size_t)(k0 + row + 32) * 64 + cg * 8, Ks + 2048 + t * 8);
            ASYNC16(Vh + (size_t)row * 1024 + k0 + cg * 8, Vs + t * 8);
            ASYNC16(Vh + (size_t)(row + 32) * 1024 + k0 + cg * 8, Vs + 2048 + t * 8);
        }
        __syncthreads();

        floatx4 st[4];
#pragma unroll
        for (int nt = 0; nt < 4; nt++) {
            int krow = nt * 16 + l16;
            bf16x8 kf0 = *(const bf16x8*)(Ks + krow * 64 + ((quad ^ s7) * 8));
            bf16x8 kf1 = *(const bf16x8*)(Ks + krow * 64 + (((quad + 4) ^ s7) * 8));
            floatx4 z = {0.f, 0.f, 0.f, 0.f};
            z = mfma32(kf0, qf0, z);
            st[nt] = mfma32(kf1, qf1, z);
        }

        short4v pf[4];
#pragma unroll
        for (int nt = 0; nt < 4; nt++) {
            floatx4 mk = *(const floatx4*)(Msall + k0 + nt * 16 + quad * 4);
#pragma unroll
            for (int r = 0; r < 4; r++) {
                float p = __expf(st[nt][r] * 0.125f + mk[r]);
                rs_acc += p;
                pf[nt][r] = (short)(__float_as_uint(p) >> 16);   // truncate to bf16
            }
        }

#pragma unroll
        for (int dt = 0; dt < 4; dt++) {
            int vrow = dt * 16 + l16;
#pragma unroll
            for (int nt = 0; nt < 4; nt++) {
                short4v vf = *(const short4v*)(Vs + vrow * 64 +
                                (((2 * nt + (quad >> 1)) ^ s7) * 8) + (quad & 1) * 4);
                o_acc[dt] = mfma16(vf, pf[nt], o_acc[dt]);
            }
        }
    }

    rs_acc += __shfl_xor(rs_acc, 16);
    rs_acc += __shfl_xor(rs_acc, 32);
    float inv_l = 1.0f / rs_acc;

    int qg = q0 + wave * 16 + l16;
#pragma unroll
    for (int dt = 0; dt < 4; dt++) {
        ushortx4 o4;
#pragma unroll
        for (int r = 0; r < 4; r++) o4[r] = f2bf(o_acc[dt][r] * inv_l);
        *(ushortx4*)(ctx + ((size_t)(b * 1024 + qg)) * 1024 + h * 64 + dt * 16 + quad * 4) = o4;
    }
}

// ---------------- out-proj GEMM + bias + residual -> x (fp32) ----------------
__global__ __launch_bounds__(256) void gemm_proj(
    const unsigned short* __restrict__ A,   // ctx bf16 [8192][1024]
    const unsigned short* __restrict__ W,   // Wo bf16 [1024][1024]
    const float* __restrict__ bo,
    const float* __restrict__ resid,        // hidden fp32 [8192][1024]
    float* __restrict__ X)
{
    __shared__ unsigned short As[128 * 32];
    __shared__ unsigned short Bs[128 * 32];
    const int K = 1024;
    const int t = threadIdx.x;
    const int wave = t >> 6, lane = t & 63;
    const int quad = lane >> 4, l16 = lane & 15;
    const int wm = (wave >> 1) * 64, wn = (wave & 1) * 64;

    const unsigned short* Ag = A + (size_t)blockIdx.x * 128 * K + (t >> 2) * K + stage_col(t);
    const unsigned short* Wg = W + (size_t)blockIdx.y * 128 * K + (t >> 2) * K + stage_col(t);

    floatx4 acc[4][4] = {};
    kloop_128<false>(Ag, Wg, As, Bs, wm, wn, l16, quad, t, acc);

#pragma unroll
    for (int nt = 0; nt < 4; nt++) {
        int gn = blockIdx.y * 128 + wn + nt * 16 + l16;
        float bias = bo[gn];
#pragma unroll
        for (int mt = 0; mt < 4; mt++) {
#pragma unroll
            for (int r = 0; r < 4; r++) {
                int gm = blockIdx.x * 128 + wm + mt * 16 + quad * 4 + r;
                size_t off = (size_t)gm * 1024 + gn;
                X[off] = acc[mt][nt][r] + bias + resid[off];
            }
        }
    }
}

// ---------------- LayerNorm: one block per token row ----------------
__global__ __launch_bounds__(256) void ln_k(const float* __restrict__ X,
                                            const float* __restrict__ g,
                                            const float* __restrict__ be,
                                            float* __restrict__ out)
{
    int row = blockIdx.x;
    int t = threadIdx.x;
    const float* xr = X + (size_t)row * 1024;
    float4 v = *(const float4*)(xr + t * 4);
    float s = v.x + v.y + v.z + v.w;
    float ss = v.x * v.x + v.y * v.y + v.z * v.z + v.w * v.w;
    for (int off = 1; off < 64; off <<= 1) {
        s += __shfl_xor(s, off);
        ss += __shfl_xor(ss, off);
    }
    __shared__ float red[8];
    int wave = t >> 6, lane = t & 63;
    if (lane == 0) { red[wave] = s; red[4 + wave] = ss; }
    __syncthreads();
    s = red[0] + red[1] + red[2] + red[3];
    ss = red[4] + red[5] + red[6] + red[7];
    float mu = s * (1.f / 1024.f);
    float var = ss * (1.f / 1024.f) - mu * mu;
    float inv = rsqrtf(var + 1e-12f);
    float4 gv = *(const float4*)(g + t * 4);
    float4 bv = *(const float4*)(be + t * 4);
    float4 o;
    o.x = (v.x - mu) * inv * gv.x + bv.x;
    o.y = (v.y - mu) * inv * gv.y + bv.y;
    o.z = (v.z - mu) * inv * gv.z + bv.z;
    o.w = (v.w - mu) * inv * gv.w + bv.w;
    *(float4*)(out + (size_t)row * 1024 + t * 4) = o;
}

extern "C" void kernel_launch(void* const* d_in, const int* in_sizes, int n_in,
                              void* d_out, int out_size, void* d_ws, size_t ws_size,
                              hipStream_t stream)
{
    const float* hidden = (const float*)d_in[0];
    const float* mask   = (const float*)d_in[1];
    const float* Wq = (const float*)d_in[2];
    const float* bq = (const float*)d_in[3];
    const float* Wk = (const float*)d_in[4];
    const float* bk = (const float*)d_in[5];
    const float* Wv = (const float*)d_in[6];
    const float* bv = (const float*)d_in[7];
    const float* Wo = (const float*)d_in[8];
    const float* bo = (const float*)d_in[9];
    const float* gamma = (const float*)d_in[10];
    const float* beta  = (const float*)d_in[11];
    float* out = (float*)d_out;

    char* ws = (char*)d_ws;
    // layout (bytes): hid_bf 16M | wqkv_bf 6M | wo_bf 2M | vt_bf 16M | ctx_bf 16M | q_bf 16M | k_bf 16M
    // x (fp32, 32M) aliases q_bf+k_bf (dead after attn). total 88M.
    unsigned short* hid_bf  = (unsigned short*)(ws + 0);
    unsigned short* wqkv_bf = (unsigned short*)(ws + 16777216);
    unsigned short* wo_bf   = (unsigned short*)(ws + 23068672);
    unsigned short* vt_bf   = (unsigned short*)(ws + 25165824);
    unsigned short* ctx_bf  = (unsigned short*)(ws + 41943040);
    unsigned short* q_bf    = (unsigned short*)(ws + 58720256);
    unsigned short* k_bf    = (unsigned short*)(ws + 75497472);
    float* x_f = (float*)(ws + 58720256);

    cvt_bf16<<<4096, 256, 0, stream>>>(hidden, hid_bf, 1048576);
    cvt_w<<<2048, 256, 0, stream>>>(Wq, Wk, Wv, Wo, wqkv_bf, wo_bf);

    gemm_qk<<<dim3(64, 16), 256, 0, stream>>>(hid_bf, wqkv_bf, bq, bk, q_bf, k_bf);
    gemm_v<<<dim3(64, 8), 256, 0, stream>>>(hid_bf, wqkv_bf + 2097152, bv, vt_bf);
    attn<<<dim3(16, 128), 256, 0, stream>>>(q_bf, k_bf, vt_bf, mask, ctx_bf);
    gemm_proj<<<dim3(64, 8), 256, 0, stream>>>(ctx_bf, wo_bf, bo, hidden, x_f);
    ln_k<<<8192, 256, 0, stream>>>(x_f, gamma, beta, out);
}

// Round 5
// 275.454 us; speedup vs baseline: 1.1215x; 1.1215x over previous
//
#include <hip/hip_runtime.h>
#include <stdint.h>

// B=8, S=1024, H=1024, NH=16, HD=64
typedef __attribute__((ext_vector_type(8))) __bf16 bf16x8;
typedef __attribute__((ext_vector_type(8))) unsigned short ushortx8;
typedef __attribute__((ext_vector_type(4))) unsigned short ushortx4;
typedef __attribute__((ext_vector_type(4))) short short4v;
typedef __attribute__((ext_vector_type(4))) float floatx4;

#define ASYNC16(g, l) __builtin_amdgcn_global_load_lds( \
    (__attribute__((address_space(1))) void*)(g),       \
    (__attribute__((address_space(3))) void*)(l), 16, 0, 0)

__device__ __forceinline__ unsigned short f2bf(float f) {
    unsigned int u = __float_as_uint(f);
    u += 0x7fffu + ((u >> 16) & 1u);   // round-to-nearest-even
    return (unsigned short)(u >> 16);
}

__device__ __forceinline__ floatx4 mfma32(bf16x8 a, bf16x8 b, floatx4 c) {
    return __builtin_amdgcn_mfma_f32_16x16x32_bf16(a, b, c, 0, 0, 0);
}
__device__ __forceinline__ floatx4 mfma16(short4v a, short4v b, floatx4 c) {
    return __builtin_amdgcn_mfma_f32_16x16x16bf16_1k(a, b, c, 0, 0, 0);
}

// ---------------- fp32 -> bf16 converts ----------------
__global__ __launch_bounds__(256) void cvt_bf16(const float* __restrict__ in,
                                                unsigned short* __restrict__ out,
                                                int n8) {
    int i = blockIdx.x * 256 + threadIdx.x;
    if (i >= n8) return;
    const float4* p = (const float4*)in + (size_t)i * 2;
    float4 a = p[0], b = p[1];
    ushortx8 o;
    o[0] = f2bf(a.x); o[1] = f2bf(a.y); o[2] = f2bf(a.z); o[3] = f2bf(a.w);
    o[4] = f2bf(b.x); o[5] = f2bf(b.y); o[6] = f2bf(b.z); o[7] = f2bf(b.w);
    *((ushortx8*)out + i) = o;
}

__global__ __launch_bounds__(256) void cvt_w(const float* __restrict__ Wq,
                                             const float* __restrict__ Wk,
                                             const float* __restrict__ Wv,
                                             const float* __restrict__ Wo,
                                             unsigned short* __restrict__ oqkv,
                                             unsigned short* __restrict__ oo) {
    int blk = blockIdx.x >> 9;
    const float* src = (blk == 0) ? Wq : (blk == 1) ? Wk : (blk == 2) ? Wv : Wo;
    unsigned short* dst = (blk == 3) ? oo : oqkv + (size_t)blk * 1048576;
    int i = (blockIdx.x & 511) * 256 + threadIdx.x;   // < 131072
    const float4* p = (const float4*)src + (size_t)i * 2;
    float4 a = p[0], b = p[1];
    ushortx8 o;
    o[0] = f2bf(a.x); o[1] = f2bf(a.y); o[2] = f2bf(a.z); o[3] = f2bf(a.w);
    o[4] = f2bf(b.x); o[5] = f2bf(b.y); o[6] = f2bf(b.z); o[7] = f2bf(b.w);
    *((ushortx8*)dst + i) = o;
}

// ---------- shared BK=64 K-loop, 128x128 tile, swizzled LDS ----------
// LDS tile: 128 rows x 64 cols (128 B row). Phys 16B-chunk p of row r holds
// logical chunk p^(r&7). Staging: thread t -> LDS offset i*4096 + t*16, i.e.
// row = i*32 + (t>>3), phys chunk = t&7, so source col = ((t&7)^((t>>3)&7))*8.
// Fragment read k-step s (k = s*32 + quad*8): phys = (s*4+quad)^(l16&7).
// SWAP=true: acc[ft][st] with C row = W-row (feat), col = A-row (s).
template<bool SWAP>
__device__ __forceinline__ void kloop_bk64(
    const unsigned short* __restrict__ Ag,  // lane-ptr (row srow, col swizzled)
    const unsigned short* __restrict__ Wg,
    unsigned short* As, unsigned short* Bs,
    int wm, int wn, int l16, int quad, int t,
    floatx4 acc[4][4])
{
#pragma unroll 1
    for (int k0 = 0; k0 < 1024; k0 += 64) {
        __syncthreads();
#pragma unroll
        for (int i = 0; i < 4; i++) {
            ASYNC16(Ag + (size_t)i * 32 * 1024 + k0, As + i * 2048 + t * 8);
            ASYNC16(Wg + (size_t)i * 32 * 1024 + k0, Bs + i * 2048 + t * 8);
        }
        __syncthreads();
#pragma unroll
        for (int s = 0; s < 2; s++) {
            int pb = ((s * 4 + quad) ^ (l16 & 7)) * 8;
            bf16x8 af[4], bfr[4];
#pragma unroll
            for (int mt = 0; mt < 4; mt++)
                af[mt] = *(const bf16x8*)(As + (wm + mt * 16 + l16) * 64 + pb);
#pragma unroll
            for (int nt = 0; nt < 4; nt++)
                bfr[nt] = *(const bf16x8*)(Bs + (wn + nt * 16 + l16) * 64 + pb);
            if (SWAP) {
#pragma unroll
                for (int ft = 0; ft < 4; ft++)
#pragma unroll
                    for (int st = 0; st < 4; st++)
                        acc[ft][st] = mfma32(bfr[ft], af[st], acc[ft][st]);
            } else {
#pragma unroll
                for (int mt = 0; mt < 4; mt++)
#pragma unroll
                    for (int nt = 0; nt < 4; nt++)
                        acc[mt][nt] = mfma32(af[mt], bfr[nt], acc[mt][nt]);
            }
        }
    }
}

// ---------------- merged QKV GEMM (SWAP compute) ----------------
// grid (64, 24): y<8 Q, y<16 K, else V. W = [Wq;Wk;Wv] [3072][1024].
__global__ __launch_bounds__(256) void gemm_qkv(
    const unsigned short* __restrict__ A,   // [8192][1024] bf16
    const unsigned short* __restrict__ W,
    const float* __restrict__ bq, const float* __restrict__ bk, const float* __restrict__ bv,
    unsigned short* __restrict__ Qo, unsigned short* __restrict__ Ko,
    unsigned short* __restrict__ Vo)        // V -> [b,h,d,s]
{
    __shared__ unsigned short As[128 * 64];
    __shared__ unsigned short Bs[128 * 64];
    const int t = threadIdx.x;
    const int wave = t >> 6, lane = t & 63;
    const int quad = lane >> 4, l16 = lane & 15;
    const int wm = (wave >> 1) * 64, wn = (wave & 1) * 64;
    const int srow = t >> 3;
    const int scol = ((t & 7) ^ (srow & 7)) * 8;

    const unsigned short* Ag = A + ((size_t)blockIdx.x * 128 + srow) * 1024 + scol;
    const unsigned short* Wg = W + ((size_t)blockIdx.y * 128 + srow) * 1024 + scol;

    floatx4 acc[4][4] = {};
    kloop_bk64<true>(Ag, Wg, As, Bs, wm, wn, l16, quad, t, acc);

    int y = blockIdx.y;
    if (y < 16) {
        // Q/K: [b,h,s,d]; lane owns 4 consecutive d (=feat row quad*4+r) -> 8B stores
        const float* bp = (y < 8) ? bq : bk;
        unsigned short* op = (y < 8) ? Qo : Ko;
#pragma unroll
        for (int ft = 0; ft < 4; ft++) {
            int featg = (y * 128 + wn + ft * 16 + quad * 4) & 1023;
            float4 b4 = *(const float4*)(bp + featg);
            int h = featg >> 6, d = featg & 63;
#pragma unroll
            for (int st = 0; st < 4; st++) {
                int sg = blockIdx.x * 128 + wm + st * 16 + l16;
                int b = sg >> 10, s = sg & 1023;
                ushortx4 o4;
                o4[0] = f2bf(acc[ft][st][0] + b4.x);
                o4[1] = f2bf(acc[ft][st][1] + b4.y);
                o4[2] = f2bf(acc[ft][st][2] + b4.z);
                o4[3] = f2bf(acc[ft][st][3] + b4.w);
                *(ushortx4*)(op + (((size_t)(b * 16 + h) * 1024 + s) * 64 + d)) = o4;
            }
        }
    } else {
        // V: [b,h,d,s]; lanes along s -> coalesced scalar stores (32B/quad segs)
#pragma unroll
        for (int ft = 0; ft < 4; ft++) {
            int featg = (y * 128 + wn + ft * 16 + quad * 4) & 1023;
            float4 b4 = *(const float4*)(bv + featg);
#pragma unroll
            for (int r = 0; r < 4; r++) {
                int feat = featg + r;
                int h = feat >> 6, d = feat & 63;
                float bias = (r == 0) ? b4.x : (r == 1) ? b4.y : (r == 2) ? b4.z : b4.w;
#pragma unroll
                for (int st = 0; st < 4; st++) {
                    int sg = blockIdx.x * 128 + wm + st * 16 + l16;
                    int b = sg >> 10, s = sg & 1023;
                    Vo[((size_t)(b * 16 + h) * 64 + d) * 1024 + s] = f2bf(acc[ft][st][r] + bias);
                }
            }
        }
    }
}

// ---------------- flash attention: 128-row Q tile ----------------
// grid (8, 128): x = 128-row q-tile, y = head. Wave w owns q rows 32w..32w+31
// (two 16-groups). S^T = K Q^T keeps P in mfma16 B-operand layout; V^T global
// layout -> vector staging. No online max (scores bounded). vf reused across
// both q-groups.
__global__ __launch_bounds__(256) void attn(
    const unsigned short* __restrict__ Q,   // [b,h,s,d]
    const unsigned short* __restrict__ Kg,  // [b,h,s,d]
    const unsigned short* __restrict__ Vt,  // [b,h,d,s]
    const float* __restrict__ mask,         // [B][S]
    unsigned short* __restrict__ ctx)       // [B,S,H] bf16
{
    __shared__ unsigned short Qs[128 * 64];
    __shared__ unsigned short Ks[64 * 64];
    __shared__ unsigned short Vs[64 * 64];  // [d][k]
    __shared__ float Msall[1024];

    const int t = threadIdx.x;
    const int wave = t >> 6, lane = t & 63, quad = lane >> 4, l16 = lane & 15;
    const int s7 = l16 & 7;
    const int head = blockIdx.y;
    const int b = head >> 4, h = head & 15;
    const int q0 = blockIdx.x * 128;
    const unsigned short* Qh = Q + (size_t)head * 65536;
    const unsigned short* Kh = Kg + (size_t)head * 65536;
    const unsigned short* Vh = Vt + (size_t)head * 65536;

    const int srow = t >> 3;
    const int scol = ((t & 7) ^ (srow & 7)) * 8;

    *(float4*)(Msall + t * 4) = *(const float4*)(mask + b * 1024 + t * 4);

    // stage Q tile [128][64] (swizzled, 4 rounds)
#pragma unroll
    for (int i = 0; i < 4; i++)
        ASYNC16(Qh + (size_t)(q0 + i * 32 + srow) * 64 + scol, Qs + i * 2048 + t * 8);
    __syncthreads();

    bf16x8 qf[2][2];
#pragma unroll
    for (int qg = 0; qg < 2; qg++) {
        int qrow = wave * 32 + qg * 16 + l16;
#pragma unroll
        for (int s = 0; s < 2; s++)
            qf[qg][s] = *(const bf16x8*)(Qs + qrow * 64 + (((s * 4 + quad) ^ s7) * 8));
    }

    float rs_acc[2] = {0.f, 0.f};
    floatx4 o_acc[2][4] = {};   // [qg][dt]: O^T rows d = dt*16+quad*4+r, col q = l16

    for (int k0 = 0; k0 < 1024; k0 += 64) {
        __syncthreads();
#pragma unroll
        for (int i = 0; i < 2; i++) {
            ASYNC16(Kh + (size_t)(k0 + i * 32 + srow) * 64 + scol, Ks + i * 2048 + t * 8);
            ASYNC16(Vh + (size_t)(i * 32 + srow) * 1024 + k0 + scol, Vs + i * 2048 + t * 8);
        }
        __syncthreads();

        // kf shared across both q-groups
        bf16x8 kf[4][2];
#pragma unroll
        for (int nt = 0; nt < 4; nt++) {
            int krow = nt * 16 + l16;
#pragma unroll
            for (int s = 0; s < 2; s++)
                kf[nt][s] = *(const bf16x8*)(Ks + krow * 64 + (((s * 4 + quad) ^ s7) * 8));
        }

        short4v pf[2][4];
#pragma unroll
        for (int qg = 0; qg < 2; qg++) {
#pragma unroll
            for (int nt = 0; nt < 4; nt++) {
                floatx4 z = {0.f, 0.f, 0.f, 0.f};
                z = mfma32(kf[nt][0], qf[qg][0], z);
                z = mfma32(kf[nt][1], qf[qg][1], z);
                floatx4 mk = *(const floatx4*)(Msall + k0 + nt * 16 + quad * 4);
#pragma unroll
                for (int r = 0; r < 4; r++) {
                    float p = __expf(z[r] * 0.125f + mk[r]);
                    rs_acc[qg] += p;
                    pf[qg][nt][r] = (short)(__float_as_uint(p) >> 16);
                }
            }
        }

        // O^T += V^T P^T; vf loaded once per (dt,nt), used by both q-groups
#pragma unroll
        for (int dt = 0; dt < 4; dt++) {
            int vrow = dt * 16 + l16;
#pragma unroll
            for (int nt = 0; nt < 4; nt++) {
                short4v vf = *(const short4v*)(Vs + vrow * 64 +
                                (((2 * nt + (quad >> 1)) ^ s7) * 8) + (quad & 1) * 4);
                o_acc[0][dt] = mfma16(vf, pf[0][nt], o_acc[0][dt]);
                o_acc[1][dt] = mfma16(vf, pf[1][nt], o_acc[1][dt]);
            }
        }
    }

#pragma unroll
    for (int qg = 0; qg < 2; qg++) {
        float v = rs_acc[qg];
        v += __shfl_xor(v, 16);
        v += __shfl_xor(v, 32);
        float inv_l = 1.0f / v;
        int qg_row = q0 + wave * 32 + qg * 16 + l16;
#pragma unroll
        for (int dt = 0; dt < 4; dt++) {
            ushortx4 o4;
#pragma unroll
            for (int r = 0; r < 4; r++) o4[r] = f2bf(o_acc[qg][dt][r] * inv_l);
            *(ushortx4*)(ctx + ((size_t)(b * 1024 + qg_row)) * 1024 + h * 64 + dt * 16 + quad * 4) = o4;
        }
    }
}

// ---------------- out-proj GEMM + bias + residual -> x (fp32) ----------------
__global__ __launch_bounds__(256) void gemm_proj(
    const unsigned short* __restrict__ A,   // ctx bf16 [8192][1024]
    const unsigned short* __restrict__ W,   // Wo bf16 [1024][1024]
    const float* __restrict__ bo,
    const float* __restrict__ resid,        // hidden fp32 [8192][1024]
    float* __restrict__ X)
{
    __shared__ unsigned short As[128 * 64];
    __shared__ unsigned short Bs[128 * 64];
    const int t = threadIdx.x;
    const int wave = t >> 6, lane = t & 63;
    const int quad = lane >> 4, l16 = lane & 15;
    const int wm = (wave >> 1) * 64, wn = (wave & 1) * 64;
    const int srow = t >> 3;
    const int scol = ((t & 7) ^ (srow & 7)) * 8;

    const unsigned short* Ag = A + ((size_t)blockIdx.x * 128 + srow) * 1024 + scol;
    const unsigned short* Wg = W + ((size_t)blockIdx.y * 128 + srow) * 1024 + scol;

    floatx4 acc[4][4] = {};
    kloop_bk64<false>(Ag, Wg, As, Bs, wm, wn, l16, quad, t, acc);

#pragma unroll
    for (int nt = 0; nt < 4; nt++) {
        int gn = blockIdx.y * 128 + wn + nt * 16 + l16;
        float bias = bo[gn];
#pragma unroll
        for (int mt = 0; mt < 4; mt++) {
#pragma unroll
            for (int r = 0; r < 4; r++) {
                int gm = blockIdx.x * 128 + wm + mt * 16 + quad * 4 + r;
                size_t off = (size_t)gm * 1024 + gn;
                X[off] = acc[mt][nt][r] + bias + resid[off];
            }
        }
    }
}

// ---------------- LayerNorm: one block per token row ----------------
__global__ __launch_bounds__(256) void ln_k(const float* __restrict__ X,
                                            const float* __restrict__ g,
                                            const float* __restrict__ be,
                                            float* __restrict__ out)
{
    int row = blockIdx.x;
    int t = threadIdx.x;
    const float* xr = X + (size_t)row * 1024;
    float4 v = *(const float4*)(xr + t * 4);
    float s = v.x + v.y + v.z + v.w;
    float ss = v.x * v.x + v.y * v.y + v.z * v.z + v.w * v.w;
    for (int off = 1; off < 64; off <<= 1) {
        s += __shfl_xor(s, off);
        ss += __shfl_xor(ss, off);
    }
    __shared__ float red[8];
    int wave = t >> 6, lane = t & 63;
    if (lane == 0) { red[wave] = s; red[4 + wave] = ss; }
    __syncthreads();
    s = red[0] + red[1] + red[2] + red[3];
    ss = red[4] + red[5] + red[6] + red[7];
    float mu = s * (1.f / 1024.f);
    float var = ss * (1.f / 1024.f) - mu * mu;
    float inv = rsqrtf(var + 1e-12f);
    float4 gv = *(const float4*)(g + t * 4);
    float4 bv = *(const float4*)(be + t * 4);
    float4 o;
    o.x = (v.x - mu) * inv * gv.x + bv.x;
    o.y = (v.y - mu) * inv * gv.y + bv.y;
    o.z = (v.z - mu) * inv * gv.z + bv.z;
    o.w = (v.w - mu) * inv * gv.w + bv.w;
    *(float4*)(out + (size_t)row * 1024 + t * 4) = o;
}

extern "C" void kernel_launch(void* const* d_in, const int* in_sizes, int n_in,
                              void* d_out, int out_size, void* d_ws, size_t ws_size,
                              hipStream_t stream)
{
    const float* hidden = (const float*)d_in[0];
    const float* mask   = (const float*)d_in[1];
    const float* Wq = (const float*)d_in[2];
    const float* bq = (const float*)d_in[3];
    const float* Wk = (const float*)d_in[4];
    const float* bk = (const float*)d_in[5];
    const float* Wv = (const float*)d_in[6];
    const float* bv = (const float*)d_in[7];
    const float* Wo = (const float*)d_in[8];
    const float* bo = (const float*)d_in[9];
    const float* gamma = (const float*)d_in[10];
    const float* beta  = (const float*)d_in[11];
    float* out = (float*)d_out;

    char* ws = (char*)d_ws;
    // layout (bytes): hid_bf 16M | wqkv_bf 6M | wo_bf 2M | vt_bf 16M | ctx_bf 16M | q_bf 16M | k_bf 16M
    // x (fp32, 32M) aliases q_bf+k_bf (dead after attn). total 88M.
    unsigned short* hid_bf  = (unsigned short*)(ws + 0);
    unsigned short* wqkv_bf = (unsigned short*)(ws + 16777216);
    unsigned short* wo_bf   = (unsigned short*)(ws + 23068672);
    unsigned short* vt_bf   = (unsigned short*)(ws + 25165824);
    unsigned short* ctx_bf  = (unsigned short*)(ws + 41943040);
    unsigned short* q_bf    = (unsigned short*)(ws + 58720256);
    unsigned short* k_bf    = (unsigned short*)(ws + 75497472);
    float* x_f = (float*)(ws + 58720256);

    cvt_bf16<<<4096, 256, 0, stream>>>(hidden, hid_bf, 1048576);
    cvt_w<<<2048, 256, 0, stream>>>(Wq, Wk, Wv, Wo, wqkv_bf, wo_bf);

    gemm_qkv<<<dim3(64, 24), 256, 0, stream>>>(hid_bf, wqkv_bf, bq, bk, bv, q_bf, k_bf, vt_bf);
    attn<<<dim3(8, 128), 256, 0, stream>>>(q_bf, k_bf, vt_bf, mask, ctx_bf);
    gemm_proj<<<dim3(64, 8), 256, 0, stream>>>(ctx_bf, wo_bf, bo, hidden, x_f);
    ln_k<<<8192, 256, 0, stream>>>(x_f, gamma, beta, out);
}